// Round 1
// baseline (326.712 us; speedup 1.0000x reference)
//
#include <hip/hip_runtime.h>
#include <cstdint>
#include <cstddef>

#define H_DIM 768
#define NHEADS 12
#define HSZ 64
#define PATCH 512
#define MTOT 16384                 // 8*4*512 tokens
#define SZT ((long)MTOT * H_DIM)   // elements per [16384,768] matrix

using short8 = __attribute__((ext_vector_type(8))) short;   // 8 bf16 (4 VGPRs)
using f32x4  = __attribute__((ext_vector_type(4))) float;   // MFMA accumulator
using us4    = __attribute__((ext_vector_type(4))) unsigned short;

// async global->LDS, 16B per lane; LDS dest = wave-uniform base + lane*16
#define GLL16(gp, lp) __builtin_amdgcn_global_load_lds( \
    (const __attribute__((address_space(1))) void*)(gp), \
    (__attribute__((address_space(3))) void*)(lp), 16, 0, 0)

// fp32 -> bf16 hi (truncate) + bf16 lo (RNE of remainder); hi+lo ~ 2^-17 rel err
__device__ __forceinline__ void split_f32(float x, unsigned short& h, unsigned short& l) {
    unsigned u = __float_as_uint(x);
    h = (unsigned short)(u >> 16);
    float rem = __uint_as_float(u & 0xffff0000u);
    float r = x - rem;                       // exact
    unsigned v = __float_as_uint(r);
    v += 0x7fff + ((v >> 16) & 1);           // RNE to bf16
    l = (unsigned short)(v >> 16);
}

__device__ __forceinline__ unsigned short bf16rne(float x) {
    unsigned v = __float_as_uint(x);
    v += 0x7fff + ((v >> 16) & 1);
    return (unsigned short)(v >> 16);
}

// ------------------------------------------------------------------
// prep_x: X fp32 [16384][768] -> X~ bf16 RNE row-major (stored in d_out)
// ------------------------------------------------------------------
__global__ __launch_bounds__(256) void prep_x(const float* __restrict__ X,
                                              unsigned short* __restrict__ Xb)
{
    const long i = ((long)blockIdx.x * 256 + threadIdx.x) * 8;
    float4 a = *(const float4*)&X[i];
    float4 b = *(const float4*)&X[i + 4];
    float xs[8] = {a.x, a.y, a.z, a.w, b.x, b.y, b.z, b.w};
    us4 h0, h1;
    #pragma unroll
    for (int j = 0; j < 4; ++j) { h0[j] = bf16rne(xs[j]); h1[j] = bf16rne(xs[j + 4]); }
    *(us4*)&Xb[i] = h0; *(us4*)&Xb[i + 4] = h1;
}

// ------------------------------------------------------------------
// prep_w: W fp32 [k][n] -> transposed bf16 [n][k]. LO=1 also writes the
// lo-residual plane (for Wo); LO=0 writes hi (RNE) only.
// ------------------------------------------------------------------
template<int LO>
__global__ __launch_bounds__(256) void prep_w(const float* __restrict__ W,
                                              unsigned short* __restrict__ Whi,
                                              unsigned short* __restrict__ Wlo)
{
    __shared__ float T[64][65];
    const int kt = blockIdx.x * 64, nt = blockIdx.y * 64;
    const int tid = threadIdx.x;
    const int r = tid >> 2, c16 = (tid & 3) * 16;
    #pragma unroll
    for (int j = 0; j < 4; ++j) {
        float4 v = *(const float4*)&W[(long)(kt + r) * H_DIM + nt + c16 + j * 4];
        T[r][c16 + j*4 + 0] = v.x; T[r][c16 + j*4 + 1] = v.y;
        T[r][c16 + j*4 + 2] = v.z; T[r][c16 + j*4 + 3] = v.w;
    }
    __syncthreads();
    unsigned short* ph = &Whi[(long)(nt + r) * H_DIM + kt + c16];
    #pragma unroll
    for (int j = 0; j < 16; ++j) {
        if (LO) {
            unsigned short hh, ll;
            split_f32(T[c16 + j][r], hh, ll);
            ph[j] = hh;
            Wlo[(long)(nt + r) * H_DIM + kt + c16 + j] = ll;
        } else {
            ph[j] = bf16rne(T[c16 + j][r]);
        }
    }
}

// ------------------------------------------------------------------
// qkv_gemm: fused Q/K/V projection, 1-pass bf16 MFMA (X~ x W~).
// grid (18, 128), XCD-bijective remap (cpx=288: each XCD owns 16 contiguous
// A-panels = 3.1 MB, L2-resident). 128x128 tile, BK=64, 4 waves.
// 2-stage counted-vmcnt pipeline: double-buffered 64 KB LDS, raw s_barrier,
// stage k+1 before compute k, s_waitcnt vmcnt(8) (never 0 mid-loop) so the
// 8 next-tile loads stay in flight across the barrier (T3/T4 minimum form).
// XOR chunk swizzle: logical chunk c of row r at phys c^(r&7) -> 2-way banks.
// Epilogues: mat0 Q tiles bf16 (pre-scaled by 0.125*log2e), mat1 K [p][d],
//            mat2 V [d][p].
// ------------------------------------------------------------------
__global__ __launch_bounds__(256, 2) void qkv_gemm(
    const unsigned short* __restrict__ Xb,
    const unsigned short* __restrict__ WqH, const unsigned short* __restrict__ WkH,
    const unsigned short* __restrict__ WvH,
    const float* __restrict__ bq, const float* __restrict__ bk, const float* __restrict__ bv,
    float qscale,
    unsigned short* __restrict__ Qt, unsigned short* __restrict__ Kp,
    unsigned short* __restrict__ Vp)
{
    __shared__ unsigned short As[16384];     // 2 bufs x 128 rows x 64 k (swizzled chunks)
    __shared__ unsigned short Bs[16384];

    // XCD-aware bijective remap: hw linear id -> logical tile id, x-fastest
    // so 18 consecutive logical ids (one A-panel) land on one XCD.
    const int s   = blockIdx.x + 18 * blockIdx.y;   // hw dispatch order
    const int lid = (s & 7) * 288 + (s >> 3);       // 2304 wgs, cpx = 288
    const int bx  = lid % 18;
    const int by  = lid / 18;

    const int mat = bx / 6;
    const int n0  = (bx % 6) * 128;
    const int m0  = by * 128;
    const unsigned short* Bh = (mat == 0) ? WqH : (mat == 1) ? WkH : WvH;
    const float* bias        = (mat == 0) ? bq  : (mat == 1) ? bk  : bv;
    const float scale        = (mat == 0) ? qscale : 1.0f;

    const int tid  = threadIdx.x;
    const int lane = tid & 63;
    const int wv   = tid >> 6;
    const int wr   = wv >> 1, wc = wv & 1;
    const int q    = lane >> 4, l15 = lane & 15;

    const int srow   = tid >> 3;                        // 0..31
    const int schunk = (tid & 7) ^ (srow & 7);          // swizzled global chunk

    char* ldsA = (char*)(&As[0]) + (wv << 10);
    char* ldsB = (char*)(&Bs[0]) + (wv << 10);

    f32x4 acc[4][4];
    #pragma unroll
    for (int i = 0; i < 4; ++i)
        #pragma unroll
        for (int j = 0; j < 4; ++j) acc[i][j] = 0;

    const int swz = (l15 & 7);   // row-dependent chunk swizzle for fragment reads

    // prologue: stage k-tile 0 into buf 0 (8 loads in flight)
    #pragma unroll
    for (int i = 0; i < 4; ++i) {
        GLL16(Xb + (long)(m0 + i * 32 + srow) * H_DIM + schunk * 8, ldsA + i * 4096);
        GLL16(Bh + (long)(n0 + i * 32 + srow) * H_DIM + schunk * 8, ldsB + i * 4096);
    }

    int kb = 0;
    for (int k0 = 0; k0 < H_DIM; k0 += 64, kb ^= 1) {
        // stage k-tile k0+64 into the other buffer; keep its 8 loads in flight
        if (k0 + 64 < H_DIM) {
            #pragma unroll
            for (int i = 0; i < 4; ++i) {
                GLL16(Xb + (long)(m0 + i * 32 + srow) * H_DIM + (k0 + 64) + schunk * 8,
                      ldsA + ((kb ^ 1) << 14) + i * 4096);
                GLL16(Bh + (long)(n0 + i * 32 + srow) * H_DIM + (k0 + 64) + schunk * 8,
                      ldsB + ((kb ^ 1) << 14) + i * 4096);
            }
            asm volatile("s_waitcnt vmcnt(8)" ::: "memory");   // cur buf landed; next 8 in flight
        } else {
            asm volatile("s_waitcnt vmcnt(0)" ::: "memory");   // last tile: drain
        }
        __builtin_amdgcn_s_barrier();            // all waves: cur buf ready
        __builtin_amdgcn_sched_barrier(0);

        const unsigned short* Ab = &As[kb << 13];
        const unsigned short* Bb = &Bs[kb << 13];
        #pragma unroll
        for (int ks = 0; ks < 2; ++ks) {
            const int pc = ((ks * 4 + q) ^ swz) * 8;
            short8 ah[4], bh[4];
            #pragma unroll
            for (int t = 0; t < 4; ++t) {
                const int mr = wr * 64 + t * 16 + l15;
                ah[t] = *(const short8*)&Ab[mr * 64 + pc];
                const int nr = wc * 64 + t * 16 + l15;
                bh[t] = *(const short8*)&Bb[nr * 64 + pc];
            }
            #pragma unroll
            for (int mt = 0; mt < 4; ++mt)
                #pragma unroll
                for (int nt = 0; nt < 4; ++nt)
                    acc[mt][nt] = __builtin_amdgcn_mfma_f32_16x16x32_bf16(ah[mt], bh[nt], acc[mt][nt], 0, 0, 0);
        }
        asm volatile("s_waitcnt lgkmcnt(0)" ::: "memory");   // all ds_reads of cur buf retired
        __builtin_amdgcn_sched_barrier(0);
        __builtin_amdgcn_s_barrier();            // safe to overwrite cur buf next iter
    }

    // epilogue: C/D layout col = lane&15, row = quad*4 + reg
    #pragma unroll
    for (int nt = 0; nt < 4; ++nt) {
        const int col = n0 + wc * 64 + nt * 16 + l15;
        const float bcol = bias[col];
        const int h = col >> 6, d = col & 63;
        #pragma unroll
        for (int mt = 0; mt < 4; ++mt) {
            const int rowB = m0 + wr * 64 + mt * 16 + q * 4;
            #pragma unroll
            for (int r = 0; r < 4; ++r) {
                const int row = rowB + r;
                const float val = (acc[mt][nt][r] + bcol) * scale;
                const int bm = row >> 9, p = row & 511;
                const int bmh = bm * NHEADS + h;
                if (mat == 0) {
                    const long idx = ((long)bmh * 8 + (p >> 6)) * 4096 + (long)(p & 63) * 64 + d;
                    Qt[idx] = bf16rne(val);
                } else if (mat == 1) {
                    Kp[(long)bmh * 32768 + (long)p * 64 + d] = bf16rne(val);
                } else {
                    Vp[(long)bmh * 32768 + (long)d * 512 + p] = bf16rne(val);
                }
            }
        }
    }
}

// ------------------------------------------------------------------
// attn2: flash attention, no max-tracking (scores bounded; base-2 softmax,
// Q pre-scaled by 0.125*log2e). QK 1-pass, PV 1-pass, all bf16.
// 128 q-rows/block, 64-key tiles, 8 iters. ctx bf16 in place over Q tiles.
// XCD remap: 4 blocks sharing one head's K/V (128 KB) land on one XCD.
// ------------------------------------------------------------------
__global__ __launch_bounds__(256, 4) void attn2(
    const unsigned short* __restrict__ Qt,
    const unsigned short* __restrict__ Kp, const unsigned short* __restrict__ Vp,
    unsigned short* __restrict__ Ctx)
{
    __shared__ unsigned short Ks[4096];      // [key][swz-chunk*8] bf16
    __shared__ unsigned short Vs[4096];      // [d][swz-chunk*8] bf16
    __shared__ unsigned short Ps[128 * 72];  // P bf16, padded stride 72
    __shared__ float red[128][2];            // cross-wave row sum (finalize)

    const int tid  = threadIdx.x;
    const int lane = tid & 63;
    const int wv   = tid >> 6;
    const int wr   = wv >> 1, wc = wv & 1;
    const int q    = lane >> 4, l15 = lane & 15;

    const int s   = blockIdx.x + 4 * blockIdx.y;    // hw dispatch order
    const int lid = (s & 7) * 192 + (s >> 3);       // 1536 wgs, cpx = 192
    const int qt2 = lid & 3;     // 0..3
    const int bmh = lid >> 2;    // 0..383

    // ---- Q fragments (loop-invariant) ----
    short8 qh[4][2];
    const long qtile = ((long)bmh * 8 + qt2 * 2 + wr) * 4096;
    #pragma unroll
    for (int mt = 0; mt < 4; ++mt)
        #pragma unroll
        for (int ks = 0; ks < 2; ++ks)
            qh[mt][ks] = *(const short8*)&Qt[qtile + (mt * 16 + l15) * 64 + ks * 32 + q * 8];

    f32x4 ctx[4][2];
    float l_cur[4][4];
    #pragma unroll
    for (int mt = 0; mt < 4; ++mt) {
        ctx[mt][0] = 0; ctx[mt][1] = 0;
        #pragma unroll
        for (int r = 0; r < 4; ++r) l_cur[mt][r] = 0.0f;
    }

    const long khead = (long)bmh * 32768;
    const int srow   = tid >> 3;                               // 0..31
    const int gchunk = ((tid & 7) ^ (srow & 7)) * 8;           // swizzled source chunk
    char* dK = (char*)&Ks[0] + (wv << 10);
    char* dV = (char*)&Vs[0] + (wv << 10);

    for (int kt = 0; kt < 8; ++kt) {
        __syncthreads();   // prev iter's QK/PV reads of Ks/Vs/Ps complete
        {
            const long kb = khead + (long)kt * 64 * 64;
            GLL16(Kp + kb + (long)srow * 64 + gchunk,        dK);
            GLL16(Kp + kb + (long)(srow + 32) * 64 + gchunk, dK + 4096);
            const long vb = khead + (long)kt * 64;
            GLL16(Vp + vb + (long)srow * 512 + gchunk,        dV);
            GLL16(Vp + vb + (long)(srow + 32) * 512 + gchunk, dV + 4096);
        }
        __syncthreads();   // staging landed (barrier drains vmcnt)

        // ---- S = Q K^T (1-pass) : rows wr*64+, keys wc*32+ ----
        f32x4 s[4][2];
        #pragma unroll
        for (int mt = 0; mt < 4; ++mt) { s[mt][0] = 0; s[mt][1] = 0; }
        short8 kf[2][2];
        #pragma unroll
        for (int nt = 0; nt < 2; ++nt)
            #pragma unroll
            for (int ks = 0; ks < 2; ++ks) {
                const int key = wc * 32 + nt * 16 + l15;
                const int phys = (q + ks * 4) ^ (key & 7);
                kf[nt][ks] = *(const short8*)&Ks[key * 64 + phys * 8];
            }
        #pragma unroll
        for (int mt = 0; mt < 4; ++mt)
            #pragma unroll
            for (int nt = 0; nt < 2; ++nt)
                #pragma unroll
                for (int ks = 0; ks < 2; ++ks)
                    s[mt][nt] = __builtin_amdgcn_mfma_f32_16x16x32_bf16(qh[mt][ks], kf[nt][ks], s[mt][nt], 0, 0, 0);

        // ---- p = exp2(s); accumulate l; write P bf16 ----
        #pragma unroll
        for (int mt = 0; mt < 4; ++mt)
            #pragma unroll
            for (int r = 0; r < 4; ++r) {
                const int row = wr * 64 + mt * 16 + q * 4 + r;
                const float p0 = __builtin_amdgcn_exp2f(s[mt][0][r]);
                const float p1 = __builtin_amdgcn_exp2f(s[mt][1][r]);
                l_cur[mt][r] += p0 + p1;
                Ps[row * 72 + wc * 32 + l15]      = bf16rne(p0);
                Ps[row * 72 + wc * 32 + 16 + l15] = bf16rne(p1);
            }
        __syncthreads();

        // ---- ctx += P V (1-pass) : rows wr*64+, d-cols wc*32+ ----
        short8 pf[4][2], vf[2][2];
        #pragma unroll
        for (int mt = 0; mt < 4; ++mt)
            #pragma unroll
            for (int ks = 0; ks < 2; ++ks)
                pf[mt][ks] = *(const short8*)&Ps[(wr * 64 + mt * 16 + l15) * 72 + ks * 32 + q * 8];
        #pragma unroll
        for (int nt = 0; nt < 2; ++nt)
            #pragma unroll
            for (int ks = 0; ks < 2; ++ks) {
                const int d = wc * 32 + nt * 16 + l15;
                const int phys = (q + ks * 4) ^ (d & 7);
                vf[nt][ks] = *(const short8*)&Vs[d * 64 + phys * 8];
            }
        #pragma unroll
        for (int mt = 0; mt < 4; ++mt)
            #pragma unroll
            for (int nt = 0; nt < 2; ++nt)
                #pragma unroll
                for (int ks = 0; ks < 2; ++ks)
                    ctx[mt][nt] = __builtin_amdgcn_mfma_f32_16x16x32_bf16(pf[mt][ks], vf[nt][ks], ctx[mt][nt], 0, 0, 0);
    }

    // ---- finalize l (in-quad + cross-wave sum), normalize, store ctx bf16 ----
    #pragma unroll
    for (int mt = 0; mt < 4; ++mt)
        #pragma unroll
        for (int r = 0; r < 4; ++r) {
            float v = l_cur[mt][r];
            v += __shfl_xor(v, 1);
            v += __shfl_xor(v, 2);
            v += __shfl_xor(v, 4);
            v += __shfl_xor(v, 8);
            if (l15 == 0) red[wr * 64 + mt * 16 + q * 4 + r][wc] = v;
        }
    __syncthreads();
    #pragma unroll
    for (int mt = 0; mt < 4; ++mt)
        #pragma unroll
        for (int r = 0; r < 4; ++r) {
            const int row = wr * 64 + mt * 16 + q * 4 + r;
            const float2 rd = *(const float2*)&red[row][0];
            const float inv = 1.0f / (rd.x + rd.y);
            const int trow = mt * 16 + q * 4 + r;
            #pragma unroll
            for (int nt = 0; nt < 2; ++nt) {
                const int col = wc * 32 + nt * 16 + l15;
                Ctx[qtile + trow * 64 + col] = bf16rne(ctx[mt][nt][r] * inv);
            }
        }
}

// ------------------------------------------------------------------
// oproj: Out = ctx @ Wo + bo, 2-pass MFMA (ctx bf16 x Wo hi/lo), BK=64.
// A from ctx tiles (stride 4096). Out fp32 row-major. 48 KB LDS.
// XCD remap: 6 blocks sharing one A-panel land on one XCD (cpx=96).
// ------------------------------------------------------------------
__global__ __launch_bounds__(256, 3) void oproj(
    const unsigned short* __restrict__ Ctx,
    const unsigned short* __restrict__ WoH, const unsigned short* __restrict__ WoL,
    const float* __restrict__ bo, float* __restrict__ out)
{
    __shared__ unsigned short As[8192];
    __shared__ unsigned short Bs[2][8192];

    const int tid  = threadIdx.x;
    const int lane = tid & 63;
    const int wv   = tid >> 6;
    const int wr   = wv >> 1, wc = wv & 1;
    const int q    = lane >> 4, l15 = lane & 15;

    const int s   = blockIdx.x + 6 * blockIdx.y;    // hw dispatch order
    const int lid = (s & 7) * 96 + (s >> 3);        // 768 wgs, cpx = 96
    const int n0  = (lid % 6) * 128;
    const int m0  = (lid / 6) * 128;

    const int srow   = tid >> 3;
    const int schunk = (tid & 7) ^ (srow & 7);

    char* ldsA = (char*)(&As[0]) + (wv << 10);
    char* ldsB = (char*)(&Bs[0][0]) + (wv << 10);

    f32x4 acc[4][4];
    #pragma unroll
    for (int i = 0; i < 4; ++i)
        #pragma unroll
        for (int j = 0; j < 4; ++j) acc[i][j] = 0;

    const int swz = (l15 & 7);

    for (int k0 = 0; k0 < H_DIM; k0 += 64) {
        const int h = k0 >> 6;   // BK=64 == head size: one head per k-iter
        #pragma unroll
        for (int i = 0; i < 4; ++i) {
            const int tok = m0 + i * 32 + srow;
            const long tile = ((long)(tok >> 9) * NHEADS + h) * 8 + ((tok >> 6) & 7);
            GLL16(Ctx + tile * 4096 + (long)(tok & 63) * 64 + schunk * 8, ldsA + i * 4096);
            GLL16(WoH + (long)(n0 + i * 32 + srow) * H_DIM + k0 + schunk * 8, ldsB + i * 4096);
            GLL16(WoL + (long)(n0 + i * 32 + srow) * H_DIM + k0 + schunk * 8, ldsB + 16384 + i * 4096);
        }
        __syncthreads();

        #pragma unroll
        for (int ks = 0; ks < 2; ++ks) {
            const int pc = ((ks * 4 + q) ^ swz) * 8;
            short8 ah[4], bh[4], bl[4];
            #pragma unroll
            for (int t = 0; t < 4; ++t) {
                const int mr = wr * 64 + t * 16 + l15;
                ah[t] = *(const short8*)&As[mr * 64 + pc];
                const int nr = wc * 64 + t * 16 + l15;
                bh[t] = *(const short8*)&Bs[0][nr * 64 + pc];
                bl[t] = *(const short8*)&Bs[1][nr * 64 + pc];
            }
            #pragma unroll
            for (int mt = 0; mt < 4; ++mt)
                #pragma unroll
                for (int nt = 0; nt < 4; ++nt) {
                    acc[mt][nt] = __builtin_amdgcn_mfma_f32_16x16x32_bf16(ah[mt], bh[nt], acc[mt][nt], 0, 0, 0);
                    acc[mt][nt] = __builtin_amdgcn_mfma_f32_16x16x32_bf16(ah[mt], bl[nt], acc[mt][nt], 0, 0, 0);
                }
        }
        __syncthreads();
    }

    #pragma unroll
    for (int nt = 0; nt < 4; ++nt) {
        const int col = n0 + wc * 64 + nt * 16 + l15;
        const float bcol = bo[col];
        #pragma unroll
        for (int mt = 0; mt < 4; ++mt) {
            const int rowB = m0 + wr * 64 + mt * 16 + q * 4;
            #pragma unroll
            for (int r = 0; r < 4; ++r)
                out[(long)(rowB + r) * H_DIM + col] = acc[mt][nt][r] + bcol;
        }
    }
}

extern "C" void kernel_launch(void* const* d_in, const int* in_sizes, int n_in,
                              void* d_out, int out_size, void* d_ws, size_t ws_size,
                              hipStream_t stream) {
    const float* X  = (const float*)d_in[0];
    const float* Wq = (const float*)d_in[1]; const float* bq = (const float*)d_in[2];
    const float* Wk = (const float*)d_in[3]; const float* bk = (const float*)d_in[4];
    const float* Wv = (const float*)d_in[5]; const float* bv = (const float*)d_in[6];
    const float* Wo = (const float*)d_in[7]; const float* bo = (const float*)d_in[8];

    unsigned short* wsu = (unsigned short*)d_ws;
    unsigned short* Qt  = wsu;                    // 12,582,912 (Q tiles bf16; ctx in place)
    unsigned short* Kp  = Qt + 12582912L;         // 12,582,912 (bf16 [bmh][p][d])
    unsigned short* Vp  = Kp + 12582912L;         // 12,582,912 (bf16 [bmh][d][p])
    unsigned short* Wt  = Vp + 12582912L;         // 5 planes x 589,824
    const long WP = (long)H_DIM * H_DIM;
    unsigned short* WqH = Wt;
    unsigned short* WkH = Wt + WP;
    unsigned short* WvH = Wt + 2 * WP;
    unsigned short* WoH = Wt + 3 * WP;
    unsigned short* WoL = Wt + 4 * WP;

    // X~ lives in d_out (dead until oproj overwrites it)
    unsigned short* Xb = (unsigned short*)d_out;

    prep_x<<<(int)(SZT / 2048), 256, 0, stream>>>(X, Xb);
    dim3 wgrid(12, 12);
    prep_w<0><<<wgrid, 256, 0, stream>>>(Wq, WqH, nullptr);
    prep_w<0><<<wgrid, 256, 0, stream>>>(Wk, WkH, nullptr);
    prep_w<0><<<wgrid, 256, 0, stream>>>(Wv, WvH, nullptr);
    prep_w<1><<<wgrid, 256, 0, stream>>>(Wo, WoH, WoL);

    const float qscale = 0.125f * 1.4426950408889634f;   // softmax in base-2 domain
    qkv_gemm<<<dim3(18, 128), 256, 0, stream>>>(Xb, WqH, WkH, WvH,
                                                bq, bk, bv, qscale, Qt, Kp, Vp);

    attn2<<<dim3(4, 384), 256, 0, stream>>>(Qt, Kp, Vp, Qt);

    oproj<<<dim3(6, 128), 256, 0, stream>>>(Qt, WoH, WoL, bo, (float*)d_out);
}